// Round 11
// baseline (122.655 us; speedup 1.0000x reference)
//
#include <hip/hip_runtime.h>

#define IMG_B 256
#define IMG_H 224
#define IMG_W 224
#define HWPIX 50176

// exact IEEE f32 ops, no contraction, matching numpy's elementwise semantics
#define FA(a,b) __fadd_rn((a),(b))
#define FM(a,b) __fmul_rn((a),(b))
#define FS(a,b) __fsub_rn((a),(b))
#define FD(a,b) __fdiv_rn((a),(b))

// python-float scalars cast to f32 exactly as numpy weak-scalar promotion does
__device__ __forceinline__ float VBF()   { return (float)(9.0/30.0*(1.9-0.1)+0.1); }
__device__ __forceinline__ float OMVBF() { return (float)(1.0 - (9.0/30.0*(1.9-0.1)+0.1)); }
__device__ __forceinline__ float VSF()   { return (float)(9.0/30.0*1.0); }

// 6 y-taps (cols j-1..j+4) from LDS row r using ONLY aligned float4 reads
__device__ __forceinline__ void lds_y6(const float* __restrict__ r, int j, float* y6) {
    const float4 vC = *(const float4*)(r + j);
    const float4 vL = *(const float4*)(r + (j > 0 ? j - 4 : 0));
    const float4 vR = *(const float4*)(r + (j + 4 < IMG_W ? j + 4 : IMG_W - 4));
    y6[0] = (j > 0) ? vL.w : 0.0f;
    y6[1] = vC.x; y6[2] = vC.y; y6[3] = vC.z; y6[4] = vC.w;
    y6[5] = (j + 4 < IMG_W) ? vR.x : 0.0f;
}

// exact blur fold (9 terms, raster order) + y1 blend, for 4 pixels
__device__ __forceinline__ void y1_from_rows(const float* yU, const float* yC,
                                             const float* yD, float* y1o) {
    const float WN = 1.0f / 13.0f, WC = 5.0f / 13.0f;
#pragma unroll
    for (int mm = 0; mm < 4; ++mm) {
        float acc = 0.0f;
        acc = FA(acc, FM(WN, yU[mm + 0]));
        acc = FA(acc, FM(WN, yU[mm + 1]));
        acc = FA(acc, FM(WN, yU[mm + 2]));
        acc = FA(acc, FM(WN, yC[mm + 0]));
        acc = FA(acc, FM(WC, yC[mm + 1]));
        acc = FA(acc, FM(WN, yC[mm + 2]));
        acc = FA(acc, FM(WN, yD[mm + 0]));
        acc = FA(acc, FM(WN, yD[mm + 1]));
        acc = FA(acc, FM(WN, yD[mm + 2]));
        y1o[mm] = FA(FM(yC[mm + 1], VBF()), FM(acc, OMVBF()));
    }
}

// prefetch raw x float4s for the 896 staged quads (rows r0-1..r0+14) into regs
__device__ __forceinline__ void stage_load(const float* __restrict__ xc, int r0,
                                           int t, float4* pf) {
#pragma unroll
    for (int u = 0; u < 4; ++u) {
        const int idx = t + 256 * u;
        float4 v = make_float4(0.f, 0.f, 0.f, 0.f);
        if (idx < 896) {
            const int row = idx / 56, c4 = (idx % 56) * 4;
            const int gi = r0 - 1 + row;
            if (gi >= 0 && gi < IMG_H)
                v = *(const float4*)(xc + (size_t)gi * IMG_W + c4);
        }
        pf[u] = v;
    }
}

// write y = s*x+m to LDS from prefetched regs; pad rows -> exact 0
__device__ __forceinline__ void stage_write(float s, float m, int r0, int t,
                                            const float4* pf, float* __restrict__ Y) {
#pragma unroll
    for (int u = 0; u < 4; ++u) {
        const int idx = t + 256 * u;
        if (idx < 896) {
            const int row = idx / 56, c4 = (idx % 56) * 4;
            const int gi = r0 - 1 + row;
            float4 w;
            if (gi >= 0 && gi < IMG_H) {
                w.x = FA(FM(pf[u].x, s), m);
                w.y = FA(FM(pf[u].y, s), m);
                w.z = FA(FM(pf[u].z, s), m);
                w.w = FA(FM(pf[u].w, s), m);
            } else {
                w.x = w.y = w.z = w.w = 0.0f;
            }
            *(float4*)(&Y[row * IMG_W + c4]) = w;
        }
    }
}

// ---- Kernel A1: one block = one 3136-px chunk (14 rows) = 32 aligned leaves of
// the numpy pairwise tree. LDS ALIASED: Y (staging) and G2/CH/LS (reduction)
// share the same 14.5 KB buffer -> 8 blocks/CU, 32 waves/CU (100% occupancy).
__global__ __launch_bounds__(256, 8) void kA1(const float* __restrict__ x,
                                              const float* __restrict__ mean_,
                                              const float* __restrict__ std_,
                                              float* __restrict__ part) {
    const int ck = blockIdx.x & 15, b = blockIdx.x >> 4;
    const int t = threadIdx.x;
    const int r0 = ck * 14;

    __shared__ float SM[3616];        // 14464 B total
    float* Y  = SM;                   // [0, 3584)  staging (live: channel loop)
    float* G2 = SM;                   // [0, 3328)  leaf-padded gray (after Y dies)
    float* CH = SM + 3328;            // [3328, 3584)
    float* LS = SM + 3584;            // [3584, 3616)

    const float CGRAY[3] = {0.299f, 0.587f, 0.114f};

    float4 pf[4];
    float4 gacc[4];

    stage_load(x + (size_t)(b * 3 + 0) * HWPIX, r0, t, pf);

    for (int c = 0; c < 3; ++c) {
        const float s = std_[c], m = mean_[c];
        stage_write(s, m, r0, t, pf, Y);
        __syncthreads();
        if (c < 2) stage_load(x + (size_t)(b * 3 + c + 1) * HWPIX, r0, t, pf);

        const float cg = CGRAY[c];
#pragma unroll
        for (int u = 0; u < 4; ++u) {
            const int qi = t + 256 * u;
            if (qi < 784) {
                const int lr = qi / 56 + 1, j = (qi % 56) * 4;
                float yU[6], yC[6], yD[6], y1[4];
                lds_y6(&Y[(lr - 1) * IMG_W], j, yU);
                lds_y6(&Y[lr * IMG_W],       j, yC);
                lds_y6(&Y[(lr + 1) * IMG_W], j, yD);
                y1_from_rows(yU, yC, yD, y1);
                float4 ga = gacc[u];
                if (c == 0) {
                    ga.x = FM(cg, y1[0]); ga.y = FM(cg, y1[1]);
                    ga.z = FM(cg, y1[2]); ga.w = FM(cg, y1[3]);
                } else {
                    ga.x = FA(ga.x, FM(cg, y1[0])); ga.y = FA(ga.y, FM(cg, y1[1]));
                    ga.z = FA(ga.z, FM(cg, y1[2])); ga.w = FA(ga.w, FM(cg, y1[3]));
                }
                gacc[u] = ga;
            }
        }
        __syncthreads();   // Y restaged next channel / Y -> G2 alias handoff
    }

    // ---- single float4 write of gray into leaf-padded G2 (aliases dead Y) ----
#pragma unroll
    for (int u = 0; u < 4; ++u) {
        const int qi = t + 256 * u;
        if (qi < 784) {
            const int pl = qi * 4;
            const int grp = pl / 392;
            const int rem = pl - grp * 392;
            int li = rem / 96; if (li > 3) li = 3;
            const int o = rem - 96 * li;
            *(float4*)(&G2[(grp * 4 + li) * 104 + o]) = gacc[u];
        }
    }
    __syncthreads();

    // ---- 8 chains per leaf (exact numpy base case); banks 2-way only ----
    {
        const int leaf = t >> 3, e = t & 7;
        const int base = leaf * 104 + e;
        const int nk = ((leaf & 3) == 3) ? 13 : 12;
        float r = G2[base];
        for (int k = 1; k < nk; ++k) r = FA(r, G2[base + 8 * k]);
        CH[t] = r;   // t == leaf*8+e
    }
    __syncthreads();

    if (t < 32) {
        const float* c8 = &CH[t * 8];
        LS[t] = FA(FA(FA(c8[0], c8[1]), FA(c8[2], c8[3])),
                   FA(FA(c8[4], c8[5]), FA(c8[6], c8[7])));
    }
    __syncthreads();

    if (t == 0) {
        float v[32];
#pragma unroll
        for (int k = 0; k < 32; ++k) v[k] = LS[k];
        for (int n = 16; n >= 1; n >>= 1)
            for (int k = 0; k < n; ++k) v[k] = FA(v[2 * k], v[2 * k + 1]);
        part[blockIdx.x] = v[0];
    }
}

// ---- Kernel B: one block = one 14-row chunk of one (b,c); staged like kA1 ----
__global__ __launch_bounds__(256) void kB(const float* __restrict__ x,
                                          const float* __restrict__ mean_,
                                          const float* __restrict__ std_,
                                          const float* __restrict__ part,
                                          float* __restrict__ out) {
    const int ck = blockIdx.x, c = blockIdx.y, b = blockIdx.z;
    const int t = threadIdx.x;
    const int r0 = ck * 14;

    __shared__ float Y[16 * IMG_W];
    __shared__ float gsh;

    const float s = std_[c], m = mean_[c];
    float4 pf[4];
    stage_load(x + (size_t)(b * 3 + c) * HWPIX, r0, t, pf);
    stage_write(s, m, r0, t, pf, Y);

    if (t == 0) {
        // exact 4-level fold of the 16 chunk roots, / 50176
        float v[16];
#pragma unroll
        for (int k = 0; k < 16; ++k) v[k] = part[b * 16 + k];
#pragma unroll
        for (int n = 8; n >= 1; n >>= 1)
#pragma unroll
            for (int k = 0; k < 8; ++k)
                if (k < n) v[k] = FA(v[2 * k], v[2 * k + 1]);
        gsh = FD(v[0], 50176.0f);
    }
    __syncthreads();
    const float g = gsh;

    float* oc = out + (size_t)(b * 3 + c) * HWPIX + (size_t)r0 * IMG_W;

    for (int qi = t; qi < 784; qi += 256) {
        const int lr = qi / 56 + 1, j = (qi % 56) * 4;
        float yU[6], yC[6], yD[6], y1[4];
        lds_y6(&Y[(lr - 1) * IMG_W], j, yU);
        lds_y6(&Y[lr * IMG_W],       j, yC);
        lds_y6(&Y[(lr + 1) * IMG_W], j, yD);
        y1_from_rows(yU, yC, yD, y1);

        float ov[4];
#pragma unroll
        for (int mm = 0; mm < 4; ++mm) {
            const float y2 = FA(FM(y1[mm], VBF()), FM(g, OMVBF()));
            const float y3 = FM(y2, VBF());
            const float y4 = (y3 < VSF()) ? y3 : FS(1.0f, y3);
            ov[mm] = FD(FS(y4, m), s);
        }
        float4 o;
        o.x = ov[0]; o.y = ov[1]; o.z = ov[2]; o.w = ov[3];
        *(float4*)(oc + (size_t)(lr - 1) * IMG_W + j) = o;
    }
}

extern "C" void kernel_launch(void* const* d_in, const int* in_sizes, int n_in,
                              void* d_out, int out_size, void* d_ws, size_t ws_size,
                              hipStream_t stream) {
    const float* x     = (const float*)d_in[0];
    const float* mean_ = (const float*)d_in[1];
    const float* std_  = (const float*)d_in[2];
    float* out = (float*)d_out;

    float* part = (float*)d_ws;   // 4096 f32 (16 chunk roots x 256 images)

    kA1<<<IMG_B * 16, 256, 0, stream>>>(x, mean_, std_, part);

    dim3 gridB(16, 3, IMG_B);
    kB<<<gridB, 256, 0, stream>>>(x, mean_, std_, part, out);
}

// Round 12
// 97.353 us; speedup vs baseline: 1.2599x; 1.2599x over previous
//
#include <hip/hip_runtime.h>

#define IMG_B 256
#define IMG_H 224
#define IMG_W 224
#define HWPIX 50176

// exact IEEE f32 ops, no contraction, matching numpy's elementwise semantics
#define FA(a,b) __fadd_rn((a),(b))
#define FM(a,b) __fmul_rn((a),(b))
#define FS(a,b) __fsub_rn((a),(b))
#define FD(a,b) __fdiv_rn((a),(b))

// python-float scalars cast to f32 exactly as numpy weak-scalar promotion does
__device__ __forceinline__ float VBF()   { return (float)(9.0/30.0*(1.9-0.1)+0.1); }
__device__ __forceinline__ float OMVBF() { return (float)(1.0 - (9.0/30.0*(1.9-0.1)+0.1)); }
__device__ __forceinline__ float VSF()   { return (float)(9.0/30.0*1.0); }

// 6 y-taps (cols j-1..j+4) from LDS row r using ONLY aligned float4 reads
__device__ __forceinline__ void lds_y6(const float* __restrict__ r, int j, float* y6) {
    const float4 vC = *(const float4*)(r + j);
    const float4 vL = *(const float4*)(r + (j > 0 ? j - 4 : 0));
    const float4 vR = *(const float4*)(r + (j + 4 < IMG_W ? j + 4 : IMG_W - 4));
    y6[0] = (j > 0) ? vL.w : 0.0f;
    y6[1] = vC.x; y6[2] = vC.y; y6[3] = vC.z; y6[4] = vC.w;
    y6[5] = (j + 4 < IMG_W) ? vR.x : 0.0f;
}

// exact blur fold (9 terms, raster order) + y1 blend, for 4 pixels
__device__ __forceinline__ void y1_from_rows(const float* yU, const float* yC,
                                             const float* yD, float* y1o) {
    const float WN = 1.0f / 13.0f, WC = 5.0f / 13.0f;
#pragma unroll
    for (int mm = 0; mm < 4; ++mm) {
        float acc = 0.0f;
        acc = FA(acc, FM(WN, yU[mm + 0]));
        acc = FA(acc, FM(WN, yU[mm + 1]));
        acc = FA(acc, FM(WN, yU[mm + 2]));
        acc = FA(acc, FM(WN, yC[mm + 0]));
        acc = FA(acc, FM(WC, yC[mm + 1]));
        acc = FA(acc, FM(WN, yC[mm + 2]));
        acc = FA(acc, FM(WN, yD[mm + 0]));
        acc = FA(acc, FM(WN, yD[mm + 1]));
        acc = FA(acc, FM(WN, yD[mm + 2]));
        y1o[mm] = FA(FM(yC[mm + 1], VBF()), FM(acc, OMVBF()));
    }
}

// prefetch raw x float4s for the 896 staged quads (rows r0-1..r0+14) into regs
__device__ __forceinline__ void stage_load(const float* __restrict__ xc, int r0,
                                           int t, float4* pf) {
#pragma unroll
    for (int u = 0; u < 4; ++u) {
        const int idx = t + 256 * u;
        float4 v = make_float4(0.f, 0.f, 0.f, 0.f);
        if (idx < 896) {
            const int row = idx / 56, c4 = (idx % 56) * 4;
            const int gi = r0 - 1 + row;
            if (gi >= 0 && gi < IMG_H)
                v = *(const float4*)(xc + (size_t)gi * IMG_W + c4);
        }
        pf[u] = v;
    }
}

// write y = s*x+m to LDS from prefetched regs; pad rows -> exact 0
__device__ __forceinline__ void stage_write(float s, float m, int r0, int t,
                                            const float4* pf, float* __restrict__ Y) {
#pragma unroll
    for (int u = 0; u < 4; ++u) {
        const int idx = t + 256 * u;
        if (idx < 896) {
            const int row = idx / 56, c4 = (idx % 56) * 4;
            const int gi = r0 - 1 + row;
            float4 w;
            if (gi >= 0 && gi < IMG_H) {
                w.x = FA(FM(pf[u].x, s), m);
                w.y = FA(FM(pf[u].y, s), m);
                w.z = FA(FM(pf[u].z, s), m);
                w.w = FA(FM(pf[u].w, s), m);
            } else {
                w.x = w.y = w.z = w.w = 0.0f;
            }
            *(float4*)(&Y[row * IMG_W + c4]) = w;
        }
    }
}

// ---- Kernel A1: one block = one 3136-px chunk (14 rows) = 32 aligned leaves of
// the numpy pairwise tree. LDS ALIASED (Y / G2+CH+LS share 14.5 KB) so LDS
// allows 11 blocks/CU; VGPR bound left at 4 waves/EU (44 regs, NO spill) so
// the runtime cap is the 32-wave slot limit -> 8 blocks/CU.
__global__ __launch_bounds__(256, 4) void kA1(const float* __restrict__ x,
                                              const float* __restrict__ mean_,
                                              const float* __restrict__ std_,
                                              float* __restrict__ part) {
    const int ck = blockIdx.x & 15, b = blockIdx.x >> 4;
    const int t = threadIdx.x;
    const int r0 = ck * 14;

    __shared__ float SM[3616];        // 14464 B total
    float* Y  = SM;                   // [0, 3584)  staging (live: channel loop)
    float* G2 = SM;                   // [0, 3328)  leaf-padded gray (after Y dies)
    float* CH = SM + 3328;            // [3328, 3584)
    float* LS = SM + 3584;            // [3584, 3616)

    const float CGRAY[3] = {0.299f, 0.587f, 0.114f};

    float4 pf[4];
    float4 gacc[4];

    stage_load(x + (size_t)(b * 3 + 0) * HWPIX, r0, t, pf);

    for (int c = 0; c < 3; ++c) {
        const float s = std_[c], m = mean_[c];
        stage_write(s, m, r0, t, pf, Y);
        __syncthreads();
        if (c < 2) stage_load(x + (size_t)(b * 3 + c + 1) * HWPIX, r0, t, pf);

        const float cg = CGRAY[c];
#pragma unroll
        for (int u = 0; u < 4; ++u) {
            const int qi = t + 256 * u;
            if (qi < 784) {
                const int lr = qi / 56 + 1, j = (qi % 56) * 4;
                float yU[6], yC[6], yD[6], y1[4];
                lds_y6(&Y[(lr - 1) * IMG_W], j, yU);
                lds_y6(&Y[lr * IMG_W],       j, yC);
                lds_y6(&Y[(lr + 1) * IMG_W], j, yD);
                y1_from_rows(yU, yC, yD, y1);
                float4 ga = gacc[u];
                if (c == 0) {
                    ga.x = FM(cg, y1[0]); ga.y = FM(cg, y1[1]);
                    ga.z = FM(cg, y1[2]); ga.w = FM(cg, y1[3]);
                } else {
                    ga.x = FA(ga.x, FM(cg, y1[0])); ga.y = FA(ga.y, FM(cg, y1[1]));
                    ga.z = FA(ga.z, FM(cg, y1[2])); ga.w = FA(ga.w, FM(cg, y1[3]));
                }
                gacc[u] = ga;
            }
        }
        __syncthreads();   // Y restaged next channel / Y -> G2 alias handoff
    }

    // ---- single float4 write of gray into leaf-padded G2 (aliases dead Y) ----
#pragma unroll
    for (int u = 0; u < 4; ++u) {
        const int qi = t + 256 * u;
        if (qi < 784) {
            const int pl = qi * 4;
            const int grp = pl / 392;
            const int rem = pl - grp * 392;
            int li = rem / 96; if (li > 3) li = 3;
            const int o = rem - 96 * li;
            *(float4*)(&G2[(grp * 4 + li) * 104 + o]) = gacc[u];
        }
    }
    __syncthreads();

    // ---- 8 chains per leaf (exact numpy base case); banks 2-way only ----
    {
        const int leaf = t >> 3, e = t & 7;
        const int base = leaf * 104 + e;
        const int nk = ((leaf & 3) == 3) ? 13 : 12;
        float r = G2[base];
        for (int k = 1; k < nk; ++k) r = FA(r, G2[base + 8 * k]);
        CH[t] = r;   // t == leaf*8+e
    }
    __syncthreads();

    if (t < 32) {
        const float* c8 = &CH[t * 8];
        LS[t] = FA(FA(FA(c8[0], c8[1]), FA(c8[2], c8[3])),
                   FA(FA(c8[4], c8[5]), FA(c8[6], c8[7])));
    }
    __syncthreads();

    if (t == 0) {
        float v[32];
#pragma unroll
        for (int k = 0; k < 32; ++k) v[k] = LS[k];
        for (int n = 16; n >= 1; n >>= 1)
            for (int k = 0; k < n; ++k) v[k] = FA(v[2 * k], v[2 * k + 1]);
        part[blockIdx.x] = v[0];
    }
}

// ---- Kernel B: one block = one 14-row chunk of one (b,c); staged like kA1 ----
__global__ __launch_bounds__(256) void kB(const float* __restrict__ x,
                                          const float* __restrict__ mean_,
                                          const float* __restrict__ std_,
                                          const float* __restrict__ part,
                                          float* __restrict__ out) {
    const int ck = blockIdx.x, c = blockIdx.y, b = blockIdx.z;
    const int t = threadIdx.x;
    const int r0 = ck * 14;

    __shared__ float Y[16 * IMG_W];
    __shared__ float gsh;

    const float s = std_[c], m = mean_[c];
    float4 pf[4];
    stage_load(x + (size_t)(b * 3 + c) * HWPIX, r0, t, pf);
    stage_write(s, m, r0, t, pf, Y);

    if (t == 0) {
        // exact 4-level fold of the 16 chunk roots, / 50176
        float v[16];
#pragma unroll
        for (int k = 0; k < 16; ++k) v[k] = part[b * 16 + k];
#pragma unroll
        for (int n = 8; n >= 1; n >>= 1)
#pragma unroll
            for (int k = 0; k < 8; ++k)
                if (k < n) v[k] = FA(v[2 * k], v[2 * k + 1]);
        gsh = FD(v[0], 50176.0f);
    }
    __syncthreads();
    const float g = gsh;

    float* oc = out + (size_t)(b * 3 + c) * HWPIX + (size_t)r0 * IMG_W;

    for (int qi = t; qi < 784; qi += 256) {
        const int lr = qi / 56 + 1, j = (qi % 56) * 4;
        float yU[6], yC[6], yD[6], y1[4];
        lds_y6(&Y[(lr - 1) * IMG_W], j, yU);
        lds_y6(&Y[lr * IMG_W],       j, yC);
        lds_y6(&Y[(lr + 1) * IMG_W], j, yD);
        y1_from_rows(yU, yC, yD, y1);

        float ov[4];
#pragma unroll
        for (int mm = 0; mm < 4; ++mm) {
            const float y2 = FA(FM(y1[mm], VBF()), FM(g, OMVBF()));
            const float y3 = FM(y2, VBF());
            const float y4 = (y3 < VSF()) ? y3 : FS(1.0f, y3);
            ov[mm] = FD(FS(y4, m), s);
        }
        float4 o;
        o.x = ov[0]; o.y = ov[1]; o.z = ov[2]; o.w = ov[3];
        *(float4*)(oc + (size_t)(lr - 1) * IMG_W + j) = o;
    }
}

extern "C" void kernel_launch(void* const* d_in, const int* in_sizes, int n_in,
                              void* d_out, int out_size, void* d_ws, size_t ws_size,
                              hipStream_t stream) {
    const float* x     = (const float*)d_in[0];
    const float* mean_ = (const float*)d_in[1];
    const float* std_  = (const float*)d_in[2];
    float* out = (float*)d_out;

    float* part = (float*)d_ws;   // 4096 f32 (16 chunk roots x 256 images)

    kA1<<<IMG_B * 16, 256, 0, stream>>>(x, mean_, std_, part);

    dim3 gridB(16, 3, IMG_B);
    kB<<<gridB, 256, 0, stream>>>(x, mean_, std_, part, out);
}

// Round 14
// 93.883 us; speedup vs baseline: 1.3065x; 1.0370x over previous
//
#include <hip/hip_runtime.h>

#define IMG_B 256
#define IMG_H 224
#define IMG_W 224
#define HWPIX 50176
#define YP 228   // kA1 LDS row pitch in dwords (224 data + 4 pad)

// exact IEEE f32 ops, no contraction, matching numpy's elementwise semantics
#define FA(a,b) __fadd_rn((a),(b))
#define FM(a,b) __fmul_rn((a),(b))
#define FS(a,b) __fsub_rn((a),(b))
#define FD(a,b) __fdiv_rn((a),(b))

// python-float scalars cast to f32 exactly as numpy weak-scalar promotion does
__device__ __forceinline__ float VBF()   { return (float)(9.0/30.0*(1.9-0.1)+0.1); }
__device__ __forceinline__ float OMVBF() { return (float)(1.0 - (9.0/30.0*(1.9-0.1)+0.1)); }
__device__ __forceinline__ float VSF()   { return (float)(9.0/30.0*1.0); }

// exact blur fold (9 terms, raster order) + y1 blend, for 4 pixels
__device__ __forceinline__ void y1_from_rows(const float* yU, const float* yC,
                                             const float* yD, float* y1o) {
    const float WN = 1.0f / 13.0f, WC = 5.0f / 13.0f;
#pragma unroll
    for (int mm = 0; mm < 4; ++mm) {
        float acc = 0.0f;
        acc = FA(acc, FM(WN, yU[mm + 0]));
        acc = FA(acc, FM(WN, yU[mm + 1]));
        acc = FA(acc, FM(WN, yU[mm + 2]));
        acc = FA(acc, FM(WN, yC[mm + 0]));
        acc = FA(acc, FM(WC, yC[mm + 1]));
        acc = FA(acc, FM(WN, yC[mm + 2]));
        acc = FA(acc, FM(WN, yD[mm + 0]));
        acc = FA(acc, FM(WN, yD[mm + 1]));
        acc = FA(acc, FM(WN, yD[mm + 2]));
        y1o[mm] = FA(FM(yC[mm + 1], VBF()), FM(acc, OMVBF()));
    }
}

// prefetch raw x float4s for the 896 staged quads (rows r0-1..r0+14) into regs
__device__ __forceinline__ void stage_load(const float* __restrict__ xc, int r0,
                                           int t, float4* pf) {
#pragma unroll
    for (int u = 0; u < 4; ++u) {
        const int idx = t + 256 * u;
        float4 v = make_float4(0.f, 0.f, 0.f, 0.f);
        if (idx < 896) {
            const int row = idx / 56, c4 = (idx % 56) * 4;
            const int gi = r0 - 1 + row;
            if (gi >= 0 && gi < IMG_H)
                v = *(const float4*)(xc + (size_t)gi * IMG_W + c4);
        }
        pf[u] = v;
    }
}

// write y = s*x+m to LDS (pitch P dwords) from prefetched regs; pad rows -> 0
__device__ __forceinline__ void stage_write(float s, float m, int r0, int t,
                                            const float4* pf, float* __restrict__ Y,
                                            int P) {
#pragma unroll
    for (int u = 0; u < 4; ++u) {
        const int idx = t + 256 * u;
        if (idx < 896) {
            const int row = idx / 56, c4 = (idx % 56) * 4;
            const int gi = r0 - 1 + row;
            float4 w;
            if (gi >= 0 && gi < IMG_H) {
                w.x = FA(FM(pf[u].x, s), m);
                w.y = FA(FM(pf[u].y, s), m);
                w.z = FA(FM(pf[u].z, s), m);
                w.w = FA(FM(pf[u].w, s), m);
            } else {
                w.x = w.y = w.z = w.w = 0.0f;
            }
            *(float4*)(&Y[row * P + c4]) = w;
        }
    }
}

// 6 y-taps from LDS (kB only; pitch 224): aligned float4 reads
__device__ __forceinline__ void lds_y6(const float* __restrict__ r, int j, float* y6) {
    const float4 vC = *(const float4*)(r + j);
    const float4 vL = *(const float4*)(r + (j > 0 ? j - 4 : 0));
    const float4 vR = *(const float4*)(r + (j + 4 < IMG_W ? j + 4 : IMG_W - 4));
    y6[0] = (j > 0) ? vL.w : 0.0f;
    y6[1] = vC.x; y6[2] = vC.y; y6[3] = vC.z; y6[4] = vC.w;
    y6[5] = (j + 4 < IMG_W) ? vR.x : 0.0f;
}

// ---- Kernel A1: one block = one 3136-px chunk (14 rows) = 32 aligned leaves.
// COLUMN-SWEEP compute: thread (col,rowgroup) slides a 3-row register window
// down its column-quad -> 1 b128 read/row; horizontal taps via lane shfl.
// Then exact chains / leaf sums / subtree root. part[b*16+ck] = root.
__global__ __launch_bounds__(256, 4) void kA1(const float* __restrict__ x,
                                              const float* __restrict__ mean_,
                                              const float* __restrict__ std_,
                                              float* __restrict__ part) {
    const int ck = blockIdx.x & 15, b = blockIdx.x >> 4;
    const int t = threadIdx.x;
    const int r0 = ck * 14;

    __shared__ float SM[3648];        // 14592 B
    float* Y  = SM;                   // [16][YP]   staging (live: channel loop)
    float* G2 = SM;                   // [0,3328)   leaf-padded gray (after Y dies)
    float* CH = SM + 3328;
    float* LS = SM + 3584;

    const float CGRAY[3] = {0.299f, 0.587f, 0.114f};

    // compute-phase roles: 224 active threads = 56 column-quads x 4 row-groups
    const int rg  = t / 56;
    const int col = t - rg * 56;
    const bool active = (t < 224);
    const int rcount = (rg < 2) ? 4 : 3;                 // rows 4,4,3,3
    const int rstart = (rg < 2) ? rg * 4 : 8 + (rg - 2) * 3;  // 0,4,8,11
    const int jd = col * 4;
    const bool lwave = ((t & 63) == 0)  && (col > 0);    // cross-wave left tap
    const bool rwave = ((t & 63) == 63) && (col < 55);   // cross-wave right tap

    float4 pf[4];
    float4 gacc[4];

    // NOTE: macro params must NOT collide with float4 member names x/y/z/w
#define LOADROW(V, LWv, RWv, yr) do {                                 \
        V   = *(const float4*)(&Y[(yr) * YP + jd]);                   \
        LWv = __shfl_up(V.w, 1, 64);                                  \
        RWv = __shfl_down(V.x, 1, 64);                                \
        if (lwave) LWv = Y[(yr) * YP + jd - 1];                       \
        if (rwave) RWv = Y[(yr) * YP + jd + 4];                       \
    } while (0)

#define FILL6(y6, V, LWv, RWv) do {                                   \
        y6[0] = (col > 0) ? LWv : 0.0f;                               \
        y6[1] = V.x; y6[2] = V.y; y6[3] = V.z; y6[4] = V.w;           \
        y6[5] = (col < 55) ? RWv : 0.0f;                              \
    } while (0)

    stage_load(x + (size_t)(b * 3 + 0) * HWPIX, r0, t, pf);

    for (int c = 0; c < 3; ++c) {
        stage_write(std_[c], mean_[c], r0, t, pf, Y, YP);
        __syncthreads();
        if (c < 2) stage_load(x + (size_t)(b * 3 + c + 1) * HWPIX, r0, t, pf);

        if (active) {
            const float cg = CGRAY[c];
            float4 v0, v1, v2;
            float la0, la1, la2, ra0, ra1, ra2;
            LOADROW(v0, la0, ra0, rstart);
            LOADROW(v1, la1, ra1, rstart + 1);
#pragma unroll
            for (int k = 0; k < 4; ++k) {
                if (k < rcount) {
                    LOADROW(v2, la2, ra2, rstart + k + 2);
                    float yU[6], yC[6], yD[6], y1[4];
                    FILL6(yU, v0, la0, ra0);
                    FILL6(yC, v1, la1, ra1);
                    FILL6(yD, v2, la2, ra2);
                    y1_from_rows(yU, yC, yD, y1);
                    float4 ga = gacc[k];
                    if (c == 0) {
                        ga.x = FM(cg, y1[0]); ga.y = FM(cg, y1[1]);
                        ga.z = FM(cg, y1[2]); ga.w = FM(cg, y1[3]);
                    } else {
                        ga.x = FA(ga.x, FM(cg, y1[0])); ga.y = FA(ga.y, FM(cg, y1[1]));
                        ga.z = FA(ga.z, FM(cg, y1[2])); ga.w = FA(ga.w, FM(cg, y1[3]));
                    }
                    gacc[k] = ga;
                    v0 = v1; la0 = la1; ra0 = ra1;
                    v1 = v2; la1 = la2; ra1 = ra2;
                }
            }
        }
        __syncthreads();   // Y restaged next channel / Y -> G2 alias handoff
    }

    // ---- write gray into leaf-padded G2 (aliases dead Y) ----
    if (active) {
#pragma unroll
        for (int k = 0; k < 4; ++k) {
            if (k < rcount) {
                const int pl = (rstart + k) * IMG_W + jd;
                const int grp = pl / 392;
                const int rem = pl - grp * 392;
                int li = rem / 96; if (li > 3) li = 3;
                const int o = rem - 96 * li;
                *(float4*)(&G2[(grp * 4 + li) * 104 + o]) = gacc[k];
            }
        }
    }
    __syncthreads();

    // ---- 8 chains per leaf (exact numpy base case); banks 2-way only ----
    {
        const int leaf = t >> 3, e = t & 7;
        const int base = leaf * 104 + e;
        const int nk = ((leaf & 3) == 3) ? 13 : 12;
        float r = G2[base];
        for (int k = 1; k < nk; ++k) r = FA(r, G2[base + 8 * k]);
        CH[t] = r;   // t == leaf*8+e
    }
    __syncthreads();

    if (t < 32) {
        const float* c8 = &CH[t * 8];
        LS[t] = FA(FA(FA(c8[0], c8[1]), FA(c8[2], c8[3])),
                   FA(FA(c8[4], c8[5]), FA(c8[6], c8[7])));
    }
    __syncthreads();

    if (t == 0) {
        float v[32];
#pragma unroll
        for (int k = 0; k < 32; ++k) v[k] = LS[k];
        for (int n = 16; n >= 1; n >>= 1)
            for (int k = 0; k < n; ++k) v[k] = FA(v[2 * k], v[2 * k + 1]);
        part[blockIdx.x] = v[0];
    }
#undef LOADROW
#undef FILL6
}

// ---- Kernel B: one block = one 14-row chunk of one (b,c); staged (UNCHANGED) ----
__global__ __launch_bounds__(256) void kB(const float* __restrict__ x,
                                          const float* __restrict__ mean_,
                                          const float* __restrict__ std_,
                                          const float* __restrict__ part,
                                          float* __restrict__ out) {
    const int ck = blockIdx.x, c = blockIdx.y, b = blockIdx.z;
    const int t = threadIdx.x;
    const int r0 = ck * 14;

    __shared__ float Y[16 * IMG_W];
    __shared__ float gsh;

    const float s = std_[c], m = mean_[c];
    float4 pf[4];
    stage_load(x + (size_t)(b * 3 + c) * HWPIX, r0, t, pf);
    stage_write(s, m, r0, t, pf, Y, IMG_W);

    if (t == 0) {
        // exact 4-level fold of the 16 chunk roots, / 50176
        float v[16];
#pragma unroll
        for (int k = 0; k < 16; ++k) v[k] = part[b * 16 + k];
#pragma unroll
        for (int n = 8; n >= 1; n >>= 1)
#pragma unroll
            for (int k = 0; k < 8; ++k)
                if (k < n) v[k] = FA(v[2 * k], v[2 * k + 1]);
        gsh = FD(v[0], 50176.0f);
    }
    __syncthreads();
    const float g = gsh;

    float* oc = out + (size_t)(b * 3 + c) * HWPIX + (size_t)r0 * IMG_W;

    for (int qi = t; qi < 784; qi += 256) {
        const int lr = qi / 56 + 1, j = (qi % 56) * 4;
        float yU[6], yC[6], yD[6], y1[4];
        lds_y6(&Y[(lr - 1) * IMG_W], j, yU);
        lds_y6(&Y[lr * IMG_W],       j, yC);
        lds_y6(&Y[(lr + 1) * IMG_W], j, yD);
        y1_from_rows(yU, yC, yD, y1);

        float ov[4];
#pragma unroll
        for (int mm = 0; mm < 4; ++mm) {
            const float y2 = FA(FM(y1[mm], VBF()), FM(g, OMVBF()));
            const float y3 = FM(y2, VBF());
            const float y4 = (y3 < VSF()) ? y3 : FS(1.0f, y3);
            ov[mm] = FD(FS(y4, m), s);
        }
        float4 o;
        o.x = ov[0]; o.y = ov[1]; o.z = ov[2]; o.w = ov[3];
        *(float4*)(oc + (size_t)(lr - 1) * IMG_W + j) = o;
    }
}

extern "C" void kernel_launch(void* const* d_in, const int* in_sizes, int n_in,
                              void* d_out, int out_size, void* d_ws, size_t ws_size,
                              hipStream_t stream) {
    const float* x     = (const float*)d_in[0];
    const float* mean_ = (const float*)d_in[1];
    const float* std_  = (const float*)d_in[2];
    float* out = (float*)d_out;

    float* part = (float*)d_ws;   // 4096 f32 (16 chunk roots x 256 images)

    kA1<<<IMG_B * 16, 256, 0, stream>>>(x, mean_, std_, part);

    dim3 gridB(16, 3, IMG_B);
    kB<<<gridB, 256, 0, stream>>>(x, mean_, std_, part, out);
}